// Round 23
// baseline (72.396 us; speedup 1.0000x reference)
//
#include <hip/hip_runtime.h>

#define NROWS 8192
#define DDIM  256
#define NBINS 129

typedef float f32x4 __attribute__((ext_vector_type(4)));
typedef short bf16x8 __attribute__((ext_vector_type(8)));
typedef long longx2 __attribute__((ext_vector_type(2)));

__device__ __forceinline__ float wave_red(float v) {
#pragma unroll
    for (int m = 32; m; m >>= 1) v += __shfl_xor(v, m, 64);
    return v;
}

__device__ __forceinline__ unsigned bfbits(float f) {
    union { float f; unsigned u; } v; v.f = f;
    return (v.u + 0x7FFFu + ((v.u >> 16) & 1u)) >> 16;
}

__device__ __forceinline__ void gload_lds16(const void* g, void* l) {
    __builtin_amdgcn_global_load_lds((const __attribute__((address_space(1))) void*)g,
                                     (__attribute__((address_space(3))) void*)l,
                                     16, 0, 0);
}

// ---------------------------------------------------------------------------
// Kernel 1: DFT basis, transposed layout basisT[288][256] bf16.
// rows 0..128: cos(2*pi*n*k/256); rows 144..272: sin; others zero.
// ---------------------------------------------------------------------------
__global__ __launch_bounds__(256) void k_basis(unsigned short* __restrict__ basisT) {
    const int n = blockIdx.x;    // 0..287
    const int k = threadIdx.x;   // 0..255
    float v = 0.0f;
    const float step = 0.0245436926f;  // 2*pi/256
    if (n < 129)                  v = cosf(step * (float)((n * k) & 255));
    else if (n >= 144 && n < 273) v = sinf(step * (float)(((n - 144) * k) & 255));
    basisT[n * DDIM + k] = (unsigned short)bfbits(v);
}

// ---------------------------------------------------------------------------
// Kernel 2 (fused row+dft), SPLIT-BINS: each 16-row tile is handled by TWO
// blocks (grid 1024 -> 4 blocks/CU, 2x the latency-hiding TLP).
//   h = bid>>9:  h=0 -> n 0..3 + spatial partial + fp8 global writes
//                h=1 -> n 4..8 (w0 takes {4,8}, w1..3 take 5..7)
// Both halves load + compute norms (needed for normalized DFT operands).
// fp8 output keeps the r20-verified fragment-pair-permuted layout.
// ---------------------------------------------------------------------------
__global__ __launch_bounds__(256) void k_prep(const float* __restrict__ clean,
                                              const float* __restrict__ turb,
                                              const unsigned short* __restrict__ basisT,
                                              unsigned char* __restrict__ cnb,
                                              unsigned char* __restrict__ tnb,
                                              float* __restrict__ spat_part,
                                              float* __restrict__ freq_part) {
    __shared__ unsigned short xn[2][16][264];   // normalized bf16, +8 pad (16.5 KB)
    __shared__ float nrm[16][2];                // row norms (max(||x||,eps))
    __shared__ float sp4[4], rbuf[4];

    const int t    = threadIdx.x;
    const int w    = t >> 6;
    const int lane = t & 63;
    const int bidx = blockIdx.x;
    const int h    = bidx >> 9;          // bin-half
    const int rbi  = bidx & 511;         // row-tile index
    const int rb   = rbi * 16;

    // ---- phase 1: coalesced load; norms; spatial partial (h=0 only) ----
    float4 xc4[4], xt4[4];
    float dsq = 0.0f;
#pragma unroll
    for (int q = 0; q < 4; ++q) {
        const int row = q * 4 + w;           // wave w owns row q*4+w
        const float* pc = clean + (rb + row) * DDIM + lane * 4;
        const float* pt = turb  + (rb + row) * DDIM + lane * 4;
        xc4[q] = *(const float4*)pc;
        xt4[q] = *(const float4*)pt;
        const float4 a = xc4[q], b = xt4[q];
        dsq += (a.x - b.x) * (a.x - b.x) + (a.y - b.y) * (a.y - b.y)
             + (a.z - b.z) * (a.z - b.z) + (a.w - b.w) * (a.w - b.w);
        float nsc = a.x * a.x + a.y * a.y + a.z * a.z + a.w * a.w;
        float nst = b.x * b.x + b.y * b.y + b.z * b.z + b.w * b.w;
        nsc = wave_red(nsc);
        nst = wave_red(nst);
        if (lane == 0) {
            nrm[row][0] = fmaxf(sqrtf(nsc), 1e-12f);
            nrm[row][1] = fmaxf(sqrtf(nst), 1e-12f);
        }
    }
    if (h == 0) {
        dsq = wave_red(dsq);
        if (lane == 0) sp4[w] = dsq;
    }
    __syncthreads();   // nrm ready

    // fragment-pair permutation for this lane's 4B fp8 store (k = lane*4)
    const int k4 = lane * 4;
    const int kl = k4 & 127;
    const int P  = (k4 & 128) + ((kl >> 6) << 6) + (((kl & 31) >> 3) << 4)
                 + (((kl >> 5) & 1) << 3) + (kl & 7);

    // ---- phase 2: normalized bf16 -> LDS; fp8 x16 -> global (h=0 only) ----
#pragma unroll
    for (int q = 0; q < 4; ++q) {
        const int row = q * 4 + w;
        const float icb = 1.0f / nrm[row][0], itb = 1.0f / nrm[row][1];
        const float4 a = xc4[q], b = xt4[q];
        uint2 pc, pt;
        pc.x = bfbits(a.x * icb) | (bfbits(a.y * icb) << 16);
        pc.y = bfbits(a.z * icb) | (bfbits(a.w * icb) << 16);
        pt.x = bfbits(b.x * itb) | (bfbits(b.y * itb) << 16);
        pt.y = bfbits(b.z * itb) | (bfbits(b.w * itb) << 16);
        *(uint2*)&xn[0][row][lane * 4] = pc;
        *(uint2*)&xn[1][row][lane * 4] = pt;
        if (h == 0) {
            const float icq = 16.0f * icb, itq = 16.0f * itb;
            int f8c = 0, f8t = 0;
            f8c = __builtin_amdgcn_cvt_pk_fp8_f32(a.x * icq, a.y * icq, f8c, false);
            f8c = __builtin_amdgcn_cvt_pk_fp8_f32(a.z * icq, a.w * icq, f8c, true);
            f8t = __builtin_amdgcn_cvt_pk_fp8_f32(b.x * itq, b.y * itq, f8t, false);
            f8t = __builtin_amdgcn_cvt_pk_fp8_f32(b.z * itq, b.w * itq, f8t, true);
            *(int*)(cnb + (rb + row) * DDIM + P) = f8c;
            *(int*)(tnb + (rb + row) * DDIM + P) = f8t;
        }
    }
    __syncthreads();   // xn ready

    // ---- phase 3: A-frags for BOTH sources from LDS ----
    const int fr = lane & 15;              // fragment row
    const int fc = (lane >> 4) << 3;       // fragment k-chunk (shorts)
    bf16x8 ac[8], at[8];
#pragma unroll
    for (int kk = 0; kk < 8; ++kk) {
        ac[kk] = *(const bf16x8*)&xn[0][fr][fc + kk * 32];
        at[kk] = *(const bf16x8*)&xn[1][fr][fc + kk * 32];
    }

    // per-lane norms for its 4 output rows (hoisted out of n-loop)
    const int lrow = (lane >> 4) << 2;
    float nc4[4], nt4[4];
#pragma unroll
    for (int r = 0; r < 4; ++r) {
        nc4[r] = nrm[lrow + r][0];
        nt4[r] = nrm[lrow + r][1];
    }

    // ---- phase 4: DFT MFMAs, 4 combos per wave, split n-range ----
    // h=0: wave w -> n=w.  h=1: w0 -> n={4,8} (step 4), w1..3 -> n=4+w.
    const int nlo   = h ? (4 + w) : w;
    const int nhi   = h ? ((w == 0) ? 9 : (5 + w)) : (w + 1);
    const int nstep = (h && w == 0) ? 4 : 1;
    const unsigned short* bcb = basisT + fr * DDIM + fc;            // cos rows
    const unsigned short* bsb = basisT + (144 + fr) * DDIM + fc;    // sin rows

    float fsum = 0.0f;
#pragma unroll 1
    for (int n = nlo; n < nhi; n += nstep) {
        f32x4 acc_cc = (f32x4){0.f, 0.f, 0.f, 0.f};
        f32x4 acc_cs = (f32x4){0.f, 0.f, 0.f, 0.f};
        f32x4 acc_tc = (f32x4){0.f, 0.f, 0.f, 0.f};
        f32x4 acc_ts = (f32x4){0.f, 0.f, 0.f, 0.f};
#pragma unroll
        for (int kk = 0; kk < 8; ++kk) {
            const bf16x8 bc = *(const bf16x8*)(bcb + n * 16 * DDIM + kk * 32);
            const bf16x8 bs = *(const bf16x8*)(bsb + n * 16 * DDIM + kk * 32);
            acc_cc = __builtin_amdgcn_mfma_f32_16x16x32_bf16(ac[kk], bc, acc_cc, 0, 0, 0);
            acc_tc = __builtin_amdgcn_mfma_f32_16x16x32_bf16(at[kk], bc, acc_tc, 0, 0, 0);
            acc_cs = __builtin_amdgcn_mfma_f32_16x16x32_bf16(ac[kk], bs, acc_cs, 0, 0, 0);
            acc_ts = __builtin_amdgcn_mfma_f32_16x16x32_bf16(at[kk], bs, acc_ts, 0, 0, 0);
        }
        // in-lane magnitude diff; bins>128 have zero basis rows -> d = 0
#pragma unroll
        for (int r = 0; r < 4; ++r) {
            const float mc = nc4[r] * sqrtf(acc_cc[r] * acc_cc[r] + acc_cs[r] * acc_cs[r]);
            const float mt = nt4[r] * sqrtf(acc_tc[r] * acc_tc[r] + acc_ts[r] * acc_ts[r]);
            const float d = mc - mt;
            fsum += d * d;
        }
    }
    fsum = wave_red(fsum);
    if (lane == 0) rbuf[w] = fsum;
    __syncthreads();
    if (t == 0) {
        freq_part[bidx] = rbuf[0] + rbuf[1] + rbuf[2] + rbuf[3];
        if (h == 0) spat_part[rbi] = sp4[0] + sp4[1] + sp4[2] + sp4[3];
    }
}

// ---------------------------------------------------------------------------
// Kernel 3: 128x128 fp8-e4m3 MFMA GEMM, fragment-pair-permuted rows
// (r20-verified 0 conflicts). kt steps 2, barriers 4. Swapped-operand
// epilogue with raw v_exp_f32 (r22-verified). Supertile XCD swizzle.
// acc = 256*cos (x16 quant each side).
// ---------------------------------------------------------------------------
#define BM 128
#define BN 128
#define BKF 128   // fp8 K-elements per tile (= 128 B per row)

__global__ __launch_bounds__(256) void k_gemm(const unsigned char* __restrict__ cnb,
                                              const unsigned char* __restrict__ tnb,
                                              const int* __restrict__ sid,
                                              float* __restrict__ pall,
                                              float* __restrict__ ppos) {
    __shared__ unsigned char As[BM][BKF];   // 16 KB
    __shared__ unsigned char Bs[BN][BKF];   // 16 KB
    __shared__ float ps[2][BM][2];          // [colhalf][row][all|pos]
    __shared__ int sidI[BM], sidJ[BN];

    // Supertile XCD swizzle: bijective (4096%8==0), ~1 MB working set/XCD.
    const int bid = blockIdx.x;
    const int xcd = bid & 7;
    const int q   = bid >> 3;            // 0..511
    const int grp = q >> 6;              // jb supertile group 0..7
    const int r   = q & 63;
    const int ib  = xcd * 8 + (r >> 3);
    const int jb  = grp * 8 + (r & 7);
    const int i0  = ib * BM;
    const int j0  = jb * BN;

    const int t = threadIdx.x;
    if (t < 128) sidI[t] = sid[i0 + t];
    else         sidJ[t - 128] = sid[j0 + t - 128];

    const int wid  = t >> 6;
    const int lane = t & 63;
    const int wrow = (wid >> 1) * 64;
    const int wcol = (wid & 1) * 64;
    const int rx   = lane & 7;

    f32x4 acc[4][4];
#pragma unroll
    for (int m = 0; m < 4; ++m)
#pragma unroll
        for (int n = 0; n < 4; ++n)
            acc[m][n] = (f32x4){0.f, 0.f, 0.f, 0.f};

    for (int kt = 0; kt < DDIM / BKF; ++kt) {   // 2 iterations
        // stage: linear LDS dest, inverse-swizzled global source (granule=16B)
#pragma unroll
        for (int it = 0; it < 4; ++it) {
            const int g  = it * 256 + t;          // 16B granule 0..1023
            const int rr = g >> 3;                // row 0..127
            const int sl = g & 7;                 // dest slot 0..7
            const int sc = (sl ^ (rr & 7)) << 4;  // source byte offset
            gload_lds16(cnb + (i0 + rr) * DDIM + kt * BKF + sc,
                        (char*)&As[0][0] + g * 16);
            gload_lds16(tnb + (j0 + rr) * DDIM + kt * BKF + sc,
                        (char*)&Bs[0][0] + g * 16);
        }
        __syncthreads();   // drains vmcnt before reads
#pragma unroll
        for (int kk2 = 0; kk2 < 2; ++kk2) {       // kk pair per b128 read
            const int gsel = kk2 * 4 + (lane >> 4);
            longx2 afp[4], bfp[4];
#pragma unroll
            for (int m = 0; m < 4; ++m) {
                const int row = wrow + m * 16 + (lane & 15);
                afp[m] = *(const longx2*)((const char*)&As[0][0]
                          + row * BKF + ((gsel ^ rx) << 4));
            }
#pragma unroll
            for (int n = 0; n < 4; ++n) {
                const int row = wcol + n * 16 + (lane & 15);
                bfp[n] = *(const longx2*)((const char*)&Bs[0][0]
                          + row * BKF + ((gsel ^ rx) << 4));
            }
            // SWAPPED: D layout -> lane&15 = cn row, in-lane r = tn col.
#pragma unroll
            for (int half = 0; half < 2; ++half)
#pragma unroll
                for (int m = 0; m < 4; ++m)
#pragma unroll
                    for (int n = 0; n < 4; ++n)
                        acc[m][n] = __builtin_amdgcn_mfma_f32_16x16x32_fp8_fp8(
                            bfp[n][half], afp[m][half], acc[m][n], 0, 0, 0);
        }
        __syncthreads();   // all reads done before next stage overwrites
    }

    // epilogue: raw v_exp_f32 + mask in registers; acc = 256*cos -> /256 in C.
    const float C = 1.442695041f / (0.07f * 256.0f);
#pragma unroll
    for (int m = 0; m < 4; ++m) {
        const int rowm = wrow + m * 16 + (lane & 15);   // this lane's row
        const int si = sidI[rowm];
        float ra = 0.0f, rp = 0.0f;
#pragma unroll
        for (int n = 0; n < 4; ++n) {
            const int cb = wcol + n * 16 + ((lane >> 4) << 2);
            const int4 sj4 = *(const int4*)&sidJ[cb];
            float e0 = __builtin_amdgcn_exp2f(acc[m][n][0] * C);
            float e1 = __builtin_amdgcn_exp2f(acc[m][n][1] * C);
            float e2 = __builtin_amdgcn_exp2f(acc[m][n][2] * C);
            float e3 = __builtin_amdgcn_exp2f(acc[m][n][3] * C);
            ra += e0 + e1 + e2 + e3;
            rp += (si == sj4.x) ? e0 : 0.0f;
            rp += (si == sj4.y) ? e1 : 0.0f;
            rp += (si == sj4.z) ? e2 : 0.0f;
            rp += (si == sj4.w) ? e3 : 0.0f;
        }
        ra += __shfl_xor(ra, 16, 64);
        ra += __shfl_xor(ra, 32, 64);
        rp += __shfl_xor(rp, 16, 64);
        rp += __shfl_xor(rp, 32, 64);
        if (lane < 16) {
            ps[wid & 1][wrow + m * 16 + lane][0] = ra;
            ps[wid & 1][wrow + m * 16 + lane][1] = rp;
        }
    }
    __syncthreads();
    if (t < BM) {
        const float sa = ps[0][t][0] + ps[1][t][0];
        const float sp = ps[0][t][1] + ps[1][t][1];
        pall[jb * NROWS + i0 + t] = sa;
        ppos[jb * NROWS + i0 + t] = sp;
    }
}

// ---------------------------------------------------------------------------
// Kernel 4: per-row sum over 64 j-block partials + log terms. Raw v_log_f32
// (log2) * ln2 — args in [~1e2, 1e10], no edge cases.
// ---------------------------------------------------------------------------
__global__ __launch_bounds__(256) void k_red(const float* __restrict__ pall,
                                             const float* __restrict__ ppos,
                                             float* __restrict__ contrib) {
    __shared__ float red[256];
    const int row = blockIdx.x * 256 + threadIdx.x;
    float sa = 0.0f, sp = 0.0f;
    for (int jb = 0; jb < 64; ++jb) {
        sa += pall[jb * NROWS + row];
        sp += ppos[jb * NROWS + row];
    }
    red[threadIdx.x] = (__builtin_amdgcn_logf(sa + 1e-8f)
                      - __builtin_amdgcn_logf(sp)) * 0.69314718056f;
    __syncthreads();
#pragma unroll
    for (int s = 128; s > 0; s >>= 1) {
        if (threadIdx.x < s) red[threadIdx.x] += red[threadIdx.x + s];
        __syncthreads();
    }
    if (threadIdx.x == 0) contrib[blockIdx.x] = red[0];
}

// ---------------------------------------------------------------------------
// Kernel 5: fold all partials -> 4 outputs (freq now 1024 entries)
// ---------------------------------------------------------------------------
__global__ __launch_bounds__(256) void k_final(const float* __restrict__ spat_part,
                                               const float* __restrict__ freq_part,
                                               const float* __restrict__ contrib,
                                               float* __restrict__ out) {
    __shared__ float reda[256], redb[256], redc[256];
    float a = 0.0f, b = 0.0f, c = 0.0f;
    for (int i = threadIdx.x; i < 512; i += 256) a += spat_part[i];
    for (int i = threadIdx.x; i < 1024; i += 256) b += freq_part[i];
    if (threadIdx.x < 32) c = contrib[threadIdx.x];
    reda[threadIdx.x] = a; redb[threadIdx.x] = b; redc[threadIdx.x] = c;
    __syncthreads();
#pragma unroll
    for (int s = 128; s > 0; s >>= 1) {
        if (threadIdx.x < s) {
            reda[threadIdx.x] += reda[threadIdx.x + s];
            redb[threadIdx.x] += redb[threadIdx.x + s];
            redc[threadIdx.x] += redc[threadIdx.x + s];
        }
        __syncthreads();
    }
    if (threadIdx.x == 0) {
        float spatial = reda[0] / (float)(NROWS * DDIM);
        float frequency = redb[0] / (float)(NROWS * NBINS);
        float contrastive = redc[0] / (float)NROWS;
        out[0] = spatial + frequency + 0.5f * contrastive;
        out[1] = spatial;
        out[2] = frequency;
        out[3] = contrastive;
    }
}

// ---------------------------------------------------------------------------
extern "C" void kernel_launch(void* const* d_in, const int* in_sizes, int n_in,
                              void* d_out, int out_size, void* d_ws, size_t ws_size,
                              hipStream_t stream) {
    const float* clean = (const float*)d_in[0];
    const float* turb  = (const float*)d_in[1];
    const int*   sids  = (const int*)d_in[2];

    char* ws = (char*)d_ws;
    unsigned char* cnb     = (unsigned char*)ws;                       // 2 MB (fp8)
    unsigned char* tnb     = (unsigned char*)(ws + 4194304);           // 2 MB (fp8)
    unsigned short* basisT = (unsigned short*)(ws + 8388608);          // 147 KB
    float* pall      = (float*)(ws + 8650752);                         // 2 MB
    float* ppos      = (float*)(ws + 10747904);                        // 2 MB
    float* spat_part = (float*)(ws + 12845056);                        // 2 KB
    float* freq_part = (float*)(ws + 12849152);                        // 4 KB
    float* contrib   = (float*)(ws + 12857344);                        // 128 B

    hipLaunchKernelGGL(k_basis, dim3(288), dim3(256), 0, stream, basisT);
    hipLaunchKernelGGL(k_prep, dim3(1024), dim3(256), 0, stream,
                       clean, turb, basisT, cnb, tnb, spat_part, freq_part);
    hipLaunchKernelGGL(k_gemm, dim3(4096), dim3(256), 0, stream,
                       cnb, tnb, sids, pall, ppos);
    hipLaunchKernelGGL(k_red, dim3(NROWS / 256), dim3(256), 0, stream,
                       pall, ppos, contrib);
    hipLaunchKernelGGL(k_final, dim3(1), dim3(256), 0, stream,
                       spat_part, freq_part, contrib, (float*)d_out);
}

// Round 24
// 70.344 us; speedup vs baseline: 1.0292x; 1.0292x over previous
//
#include <hip/hip_runtime.h>

#define NROWS 8192
#define DDIM  256
#define NBINS 129

typedef float f32x4 __attribute__((ext_vector_type(4)));
typedef short bf16x8 __attribute__((ext_vector_type(8)));
typedef long longx2 __attribute__((ext_vector_type(2)));

__device__ __forceinline__ float wave_red(float v) {
#pragma unroll
    for (int m = 32; m; m >>= 1) v += __shfl_xor(v, m, 64);
    return v;
}

__device__ __forceinline__ unsigned bfbits(float f) {
    union { float f; unsigned u; } v; v.f = f;
    return (v.u + 0x7FFFu + ((v.u >> 16) & 1u)) >> 16;
}

__device__ __forceinline__ void gload_lds16(const void* g, void* l) {
    __builtin_amdgcn_global_load_lds((const __attribute__((address_space(1))) void*)g,
                                     (__attribute__((address_space(3))) void*)l,
                                     16, 0, 0);
}

// ---------------------------------------------------------------------------
// Kernel 1: DFT basis, transposed layout basisT[288][256] bf16.
// rows 0..128: cos(2*pi*n*k/256); rows 144..272: sin; others zero.
// ---------------------------------------------------------------------------
__global__ __launch_bounds__(256) void k_basis(unsigned short* __restrict__ basisT) {
    const int n = blockIdx.x;    // 0..287
    const int k = threadIdx.x;   // 0..255
    float v = 0.0f;
    const float step = 0.0245436926f;  // 2*pi/256
    if (n < 129)                  v = cosf(step * (float)((n * k) & 255));
    else if (n >= 144 && n < 273) v = sinf(step * (float)(((n - 144) * k) & 255));
    basisT[n * DDIM + k] = (unsigned short)bfbits(v);
}

// ---------------------------------------------------------------------------
// Kernel 2 (fused row+dft), NO-EXCHANGE (r16-best) + fp8 e4m3 GEMM-operand
// output in FRAGMENT-PAIR-PERMUTED row layout (r20-verified: 0 bank
// conflicts): byte P = kk2*64 + h*16 + half*8 + b holds logical
// k = (2kk2+half)*32 + h*8 + b within each 128B kt-half.
// ---------------------------------------------------------------------------
__global__ __launch_bounds__(256) void k_prep(const float* __restrict__ clean,
                                              const float* __restrict__ turb,
                                              const unsigned short* __restrict__ basisT,
                                              unsigned char* __restrict__ cnb,
                                              unsigned char* __restrict__ tnb,
                                              float* __restrict__ spat_part,
                                              float* __restrict__ freq_part) {
    __shared__ unsigned short xn[2][16][264];   // normalized bf16, +8 pad (16.5 KB)
    __shared__ float nrm[16][2];                // row norms (max(||x||,eps))
    __shared__ float sp4[4], rbuf[4];

    const int t    = threadIdx.x;
    const int w    = t >> 6;
    const int lane = t & 63;
    const int rb   = blockIdx.x * 16;

    // ---- phase 1: coalesced load; norms; spatial partial ----
    float4 xc4[4], xt4[4];
    float dsq = 0.0f;
#pragma unroll
    for (int q = 0; q < 4; ++q) {
        const int row = q * 4 + w;           // wave w owns row q*4+w
        const float* pc = clean + (rb + row) * DDIM + lane * 4;
        const float* pt = turb  + (rb + row) * DDIM + lane * 4;
        xc4[q] = *(const float4*)pc;
        xt4[q] = *(const float4*)pt;
        const float4 a = xc4[q], b = xt4[q];
        dsq += (a.x - b.x) * (a.x - b.x) + (a.y - b.y) * (a.y - b.y)
             + (a.z - b.z) * (a.z - b.z) + (a.w - b.w) * (a.w - b.w);
        float nsc = a.x * a.x + a.y * a.y + a.z * a.z + a.w * a.w;
        float nst = b.x * b.x + b.y * b.y + b.z * b.z + b.w * b.w;
        nsc = wave_red(nsc);
        nst = wave_red(nst);
        if (lane == 0) {
            nrm[row][0] = fmaxf(sqrtf(nsc), 1e-12f);
            nrm[row][1] = fmaxf(sqrtf(nst), 1e-12f);
        }
    }
    dsq = wave_red(dsq);
    if (lane == 0) sp4[w] = dsq;
    __syncthreads();   // nrm ready

    // fragment-pair permutation for this lane's 4B fp8 store (k = lane*4)
    const int k4 = lane * 4;
    const int kl = k4 & 127;
    const int P  = (k4 & 128) + ((kl >> 6) << 6) + (((kl & 31) >> 3) << 4)
                 + (((kl >> 5) & 1) << 3) + (kl & 7);

    // ---- phase 2: normalized bf16 -> LDS (DFT) and fp8 x16 -> global ----
#pragma unroll
    for (int q = 0; q < 4; ++q) {
        const int row = q * 4 + w;
        const float icb = 1.0f / nrm[row][0], itb = 1.0f / nrm[row][1];
        const float icq = 16.0f * icb, itq = 16.0f * itb;
        const float4 a = xc4[q], b = xt4[q];
        uint2 pc, pt;
        pc.x = bfbits(a.x * icb) | (bfbits(a.y * icb) << 16);
        pc.y = bfbits(a.z * icb) | (bfbits(a.w * icb) << 16);
        pt.x = bfbits(b.x * itb) | (bfbits(b.y * itb) << 16);
        pt.y = bfbits(b.z * itb) | (bfbits(b.w * itb) << 16);
        *(uint2*)&xn[0][row][lane * 4] = pc;
        *(uint2*)&xn[1][row][lane * 4] = pt;
        int f8c = 0, f8t = 0;
        f8c = __builtin_amdgcn_cvt_pk_fp8_f32(a.x * icq, a.y * icq, f8c, false);
        f8c = __builtin_amdgcn_cvt_pk_fp8_f32(a.z * icq, a.w * icq, f8c, true);
        f8t = __builtin_amdgcn_cvt_pk_fp8_f32(b.x * itq, b.y * itq, f8t, false);
        f8t = __builtin_amdgcn_cvt_pk_fp8_f32(b.z * itq, b.w * itq, f8t, true);
        *(int*)(cnb + (rb + row) * DDIM + P) = f8c;
        *(int*)(tnb + (rb + row) * DDIM + P) = f8t;
    }
    __syncthreads();   // xn ready

    // ---- phase 3: A-frags for BOTH sources from LDS ----
    const int fr = lane & 15;              // fragment row
    const int fc = (lane >> 4) << 3;       // fragment k-chunk (shorts)
    bf16x8 ac[8], at[8];
#pragma unroll
    for (int kk = 0; kk < 8; ++kk) {
        ac[kk] = *(const bf16x8*)&xn[0][fr][fc + kk * 32];
        at[kk] = *(const bf16x8*)&xn[1][fr][fc + kk * 32];
    }

    // per-lane norms for its 4 output rows (hoisted out of n-loop)
    const int lrow = (lane >> 4) << 2;
    float nc4[4], nt4[4];
#pragma unroll
    for (int r = 0; r < 4; ++r) {
        nc4[r] = nrm[lrow + r][0];
        nt4[r] = nrm[lrow + r][1];
    }

    // ---- phase 4: DFT MFMAs, all 4 combos per wave, n-quarter split ----
    const int nlo = (w == 0) ? 0 : (w * 2 + 1);
    const int nhi = (w == 0) ? 3 : (w * 2 + 3);
    const unsigned short* bcb = basisT + fr * DDIM + fc;            // cos rows
    const unsigned short* bsb = basisT + (144 + fr) * DDIM + fc;    // sin rows

    float fsum = 0.0f;
#pragma unroll 1
    for (int n = nlo; n < nhi; ++n) {
        f32x4 acc_cc = (f32x4){0.f, 0.f, 0.f, 0.f};
        f32x4 acc_cs = (f32x4){0.f, 0.f, 0.f, 0.f};
        f32x4 acc_tc = (f32x4){0.f, 0.f, 0.f, 0.f};
        f32x4 acc_ts = (f32x4){0.f, 0.f, 0.f, 0.f};
#pragma unroll
        for (int kk = 0; kk < 8; ++kk) {
            const bf16x8 bc = *(const bf16x8*)(bcb + n * 16 * DDIM + kk * 32);
            const bf16x8 bs = *(const bf16x8*)(bsb + n * 16 * DDIM + kk * 32);
            acc_cc = __builtin_amdgcn_mfma_f32_16x16x32_bf16(ac[kk], bc, acc_cc, 0, 0, 0);
            acc_tc = __builtin_amdgcn_mfma_f32_16x16x32_bf16(at[kk], bc, acc_tc, 0, 0, 0);
            acc_cs = __builtin_amdgcn_mfma_f32_16x16x32_bf16(ac[kk], bs, acc_cs, 0, 0, 0);
            acc_ts = __builtin_amdgcn_mfma_f32_16x16x32_bf16(at[kk], bs, acc_ts, 0, 0, 0);
        }
        // in-lane magnitude diff; bins>128 have zero basis rows -> d = 0
#pragma unroll
        for (int r = 0; r < 4; ++r) {
            const float mc = nc4[r] * sqrtf(acc_cc[r] * acc_cc[r] + acc_cs[r] * acc_cs[r]);
            const float mt = nt4[r] * sqrtf(acc_tc[r] * acc_tc[r] + acc_ts[r] * acc_ts[r]);
            const float d = mc - mt;
            fsum += d * d;
        }
    }
    fsum = wave_red(fsum);
    if (lane == 0) rbuf[w] = fsum;
    __syncthreads();
    if (t == 0) {
        freq_part[blockIdx.x] = rbuf[0] + rbuf[1] + rbuf[2] + rbuf[3];
        spat_part[blockIdx.x] = sp4[0] + sp4[1] + sp4[2] + sp4[3];
    }
}

// ---------------------------------------------------------------------------
// Kernel 3: 128x128 fp8-e4m3 MFMA GEMM, fragment-pair-permuted rows
// (r20-verified 0 conflicts). kt steps 2, barriers 4, staging halved vs
// bf16. Swapped-operand epilogue with raw v_exp_f32 (r22-verified -5.3 us).
// Supertile XCD swizzle. acc = 256*cos.
// ---------------------------------------------------------------------------
#define BM 128
#define BN 128
#define BKF 128   // fp8 K-elements per tile (= 128 B per row)

__global__ __launch_bounds__(256) void k_gemm(const unsigned char* __restrict__ cnb,
                                              const unsigned char* __restrict__ tnb,
                                              const int* __restrict__ sid,
                                              float* __restrict__ pall,
                                              float* __restrict__ ppos) {
    __shared__ unsigned char As[BM][BKF];   // 16 KB
    __shared__ unsigned char Bs[BN][BKF];   // 16 KB
    __shared__ float ps[2][BM][2];          // [colhalf][row][all|pos]
    __shared__ int sidI[BM], sidJ[BN];

    // Supertile XCD swizzle: bijective (4096%8==0), ~1 MB working set/XCD.
    const int bid = blockIdx.x;
    const int xcd = bid & 7;
    const int q   = bid >> 3;            // 0..511
    const int grp = q >> 6;              // jb supertile group 0..7
    const int r   = q & 63;
    const int ib  = xcd * 8 + (r >> 3);
    const int jb  = grp * 8 + (r & 7);
    const int i0  = ib * BM;
    const int j0  = jb * BN;

    const int t = threadIdx.x;
    if (t < 128) sidI[t] = sid[i0 + t];
    else         sidJ[t - 128] = sid[j0 + t - 128];

    const int wid  = t >> 6;
    const int lane = t & 63;
    const int wrow = (wid >> 1) * 64;
    const int wcol = (wid & 1) * 64;
    const int rx   = lane & 7;

    f32x4 acc[4][4];
#pragma unroll
    for (int m = 0; m < 4; ++m)
#pragma unroll
        for (int n = 0; n < 4; ++n)
            acc[m][n] = (f32x4){0.f, 0.f, 0.f, 0.f};

    for (int kt = 0; kt < DDIM / BKF; ++kt) {   // 2 iterations
        // stage: linear LDS dest, inverse-swizzled global source (granule=16B)
#pragma unroll
        for (int it = 0; it < 4; ++it) {
            const int g  = it * 256 + t;          // 16B granule 0..1023
            const int rr = g >> 3;                // row 0..127
            const int sl = g & 7;                 // dest slot 0..7
            const int sc = (sl ^ (rr & 7)) << 4;  // source byte offset
            gload_lds16(cnb + (i0 + rr) * DDIM + kt * BKF + sc,
                        (char*)&As[0][0] + g * 16);
            gload_lds16(tnb + (j0 + rr) * DDIM + kt * BKF + sc,
                        (char*)&Bs[0][0] + g * 16);
        }
        __syncthreads();   // drains vmcnt before reads
#pragma unroll
        for (int kk2 = 0; kk2 < 2; ++kk2) {       // kk pair per b128 read
            const int gsel = kk2 * 4 + (lane >> 4);
            longx2 afp[4], bfp[4];
#pragma unroll
            for (int m = 0; m < 4; ++m) {
                const int row = wrow + m * 16 + (lane & 15);
                afp[m] = *(const longx2*)((const char*)&As[0][0]
                          + row * BKF + ((gsel ^ rx) << 4));
            }
#pragma unroll
            for (int n = 0; n < 4; ++n) {
                const int row = wcol + n * 16 + (lane & 15);
                bfp[n] = *(const longx2*)((const char*)&Bs[0][0]
                          + row * BKF + ((gsel ^ rx) << 4));
            }
            // SWAPPED: D layout -> lane&15 = cn row, in-lane r = tn col.
#pragma unroll
            for (int half = 0; half < 2; ++half)
#pragma unroll
                for (int m = 0; m < 4; ++m)
#pragma unroll
                    for (int n = 0; n < 4; ++n)
                        acc[m][n] = __builtin_amdgcn_mfma_f32_16x16x32_fp8_fp8(
                            bfp[n][half], afp[m][half], acc[m][n], 0, 0, 0);
        }
        __syncthreads();   // all reads done before next stage overwrites
    }

    // epilogue: raw v_exp_f32 + mask in registers; acc = 256*cos -> /256 in C.
    const float C = 1.442695041f / (0.07f * 256.0f);
#pragma unroll
    for (int m = 0; m < 4; ++m) {
        const int rowm = wrow + m * 16 + (lane & 15);   // this lane's row
        const int si = sidI[rowm];
        float ra = 0.0f, rp = 0.0f;
#pragma unroll
        for (int n = 0; n < 4; ++n) {
            const int cb = wcol + n * 16 + ((lane >> 4) << 2);
            const int4 sj4 = *(const int4*)&sidJ[cb];
            float e0 = __builtin_amdgcn_exp2f(acc[m][n][0] * C);
            float e1 = __builtin_amdgcn_exp2f(acc[m][n][1] * C);
            float e2 = __builtin_amdgcn_exp2f(acc[m][n][2] * C);
            float e3 = __builtin_amdgcn_exp2f(acc[m][n][3] * C);
            ra += e0 + e1 + e2 + e3;
            rp += (si == sj4.x) ? e0 : 0.0f;
            rp += (si == sj4.y) ? e1 : 0.0f;
            rp += (si == sj4.z) ? e2 : 0.0f;
            rp += (si == sj4.w) ? e3 : 0.0f;
        }
        ra += __shfl_xor(ra, 16, 64);
        ra += __shfl_xor(ra, 32, 64);
        rp += __shfl_xor(rp, 16, 64);
        rp += __shfl_xor(rp, 32, 64);
        if (lane < 16) {
            ps[wid & 1][wrow + m * 16 + lane][0] = ra;
            ps[wid & 1][wrow + m * 16 + lane][1] = rp;
        }
    }
    __syncthreads();
    if (t < BM) {
        const float sa = ps[0][t][0] + ps[1][t][0];
        const float sp = ps[0][t][1] + ps[1][t][1];
        pall[jb * NROWS + i0 + t] = sa;
        ppos[jb * NROWS + i0 + t] = sp;
    }
}

// ---------------------------------------------------------------------------
// Kernel 4: per-row sum over 64 j-block partials + log terms. Raw v_log_f32
// (log2) * ln2 — args in [~1e2, 1e10], no edge cases.
// ---------------------------------------------------------------------------
__global__ __launch_bounds__(256) void k_red(const float* __restrict__ pall,
                                             const float* __restrict__ ppos,
                                             float* __restrict__ contrib) {
    __shared__ float red[256];
    const int row = blockIdx.x * 256 + threadIdx.x;
    float sa = 0.0f, sp = 0.0f;
    for (int jb = 0; jb < 64; ++jb) {
        sa += pall[jb * NROWS + row];
        sp += ppos[jb * NROWS + row];
    }
    red[threadIdx.x] = (__builtin_amdgcn_logf(sa + 1e-8f)
                      - __builtin_amdgcn_logf(sp)) * 0.69314718056f;
    __syncthreads();
#pragma unroll
    for (int s = 128; s > 0; s >>= 1) {
        if (threadIdx.x < s) red[threadIdx.x] += red[threadIdx.x + s];
        __syncthreads();
    }
    if (threadIdx.x == 0) contrib[blockIdx.x] = red[0];
}

// ---------------------------------------------------------------------------
// Kernel 5: fold all partials -> 4 outputs
// ---------------------------------------------------------------------------
__global__ __launch_bounds__(256) void k_final(const float* __restrict__ spat_part,
                                               const float* __restrict__ freq_part,
                                               const float* __restrict__ contrib,
                                               float* __restrict__ out) {
    __shared__ float reda[256], redb[256], redc[256];
    float a = 0.0f, b = 0.0f, c = 0.0f;
    for (int i = threadIdx.x; i < 512; i += 256) {
        a += spat_part[i];
        b += freq_part[i];
    }
    if (threadIdx.x < 32) c = contrib[threadIdx.x];
    reda[threadIdx.x] = a; redb[threadIdx.x] = b; redc[threadIdx.x] = c;
    __syncthreads();
#pragma unroll
    for (int s = 128; s > 0; s >>= 1) {
        if (threadIdx.x < s) {
            reda[threadIdx.x] += reda[threadIdx.x + s];
            redb[threadIdx.x] += redb[threadIdx.x + s];
            redc[threadIdx.x] += redc[threadIdx.x + s];
        }
        __syncthreads();
    }
    if (threadIdx.x == 0) {
        float spatial = reda[0] / (float)(NROWS * DDIM);
        float frequency = redb[0] / (float)(NROWS * NBINS);
        float contrastive = redc[0] / (float)NROWS;
        out[0] = spatial + frequency + 0.5f * contrastive;
        out[1] = spatial;
        out[2] = frequency;
        out[3] = contrastive;
    }
}

// ---------------------------------------------------------------------------
extern "C" void kernel_launch(void* const* d_in, const int* in_sizes, int n_in,
                              void* d_out, int out_size, void* d_ws, size_t ws_size,
                              hipStream_t stream) {
    const float* clean = (const float*)d_in[0];
    const float* turb  = (const float*)d_in[1];
    const int*   sids  = (const int*)d_in[2];

    char* ws = (char*)d_ws;
    unsigned char* cnb     = (unsigned char*)ws;                       // 2 MB (fp8)
    unsigned char* tnb     = (unsigned char*)(ws + 4194304);           // 2 MB (fp8)
    unsigned short* basisT = (unsigned short*)(ws + 8388608);          // 147 KB
    float* pall      = (float*)(ws + 8650752);                         // 2 MB
    float* ppos      = (float*)(ws + 10747904);                        // 2 MB
    float* spat_part = (float*)(ws + 12845056);                        // 2 KB
    float* freq_part = (float*)(ws + 12849152);                        // 2 KB
    float* contrib   = (float*)(ws + 12853248);                        // 128 B

    hipLaunchKernelGGL(k_basis, dim3(288), dim3(256), 0, stream, basisT);
    hipLaunchKernelGGL(k_prep, dim3(NROWS / 16), dim3(256), 0, stream,
                       clean, turb, basisT, cnb, tnb, spat_part, freq_part);
    hipLaunchKernelGGL(k_gemm, dim3(4096), dim3(256), 0, stream,
                       cnb, tnb, sids, pall, ppos);
    hipLaunchKernelGGL(k_red, dim3(NROWS / 256), dim3(256), 0, stream,
                       pall, ppos, contrib);
    hipLaunchKernelGGL(k_final, dim3(1), dim3(256), 0, stream,
                       spat_part, freq_part, contrib, (float*)d_out);
}